// Round 3
// baseline (735.225 us; speedup 1.0000x reference)
//
#include <hip/hip_runtime.h>

// RiRoIAlignRotated: features (B=2, C=256, H=256, W=256) f32, rois (R=512, 6)
// out (R, C, 7, 7) f32.  C = Cg(32) * O(8), orientation o fastest in channel.
// P = 7, S = 2 (2x2 samples per bin), SCALE = 0.25, counter-clockwise.

#define NORI 8
#define PBIN 7
#define NSAMP 2

__global__ __launch_bounds__(256) void riroi_align_rotated_kernel(
    const float* __restrict__ feat,   // (B, C, H, W)
    const float* __restrict__ rois,   // (R, 6)
    float* __restrict__ out,          // (R, C, P, P)
    int C, int H, int W)
{
    const int blk = blockIdx.x;
    const int r   = blk / (PBIN * PBIN);
    const int pix = blk % (PBIN * PBIN);
    const int ph  = pix / PBIN;
    const int pw  = pix % PBIN;
    const int c   = threadIdx.x;      // channel 0..255
    const int o   = c & (NORI - 1);   // orientation (fastest channel dim)

    // ---- per-roi params (block-uniform; compiler scalarizes) ----
    const float* roi = rois + r * 6;
    const int   b     = (int)roi[0];
    const float cx    = roi[1] * 0.25f;
    const float cy    = roi[2] * 0.25f;
    const float rw    = fmaxf(roi[3] * 0.25f, 1.0f);
    const float rh    = fmaxf(roi[4] * 0.25f, 1.0f);
    const float theta = roi[5];

    // orientation index + blend factors: ind_f = theta * O / (2*pi)
    const float ind_f     = theta * (8.0f / 6.283185307179586f);
    const float ind_floor = floorf(ind_f);
    const float l_var     = ind_f - ind_floor;
    const float r_var     = 1.0f - l_var;
    // jnp.mod on int32: result has sign of divisor (non-negative here)
    const int ind = (((int)ind_floor % NORI) + NORI) % NORI;

    const float bin_h = rh * (1.0f / (float)PBIN);
    const float bin_w = rw * (1.0f / (float)PBIN);
    const float ct = cosf(theta);
    const float st = sinf(theta);

    const float* __restrict__ fbc = feat + ((size_t)b * C + c) * (size_t)(H * W);
    const float Hf = (float)H, Wf = (float)W;

    const float y_base = -rh * 0.5f + (float)ph * bin_h;
    const float x_base = -rw * 0.5f + (float)pw * bin_w;

    float acc = 0.0f;
    #pragma unroll
    for (int sy = 0; sy < NSAMP; ++sy) {
        #pragma unroll
        for (int sx = 0; sx < NSAMP; ++sx) {
            // sample coords in roi frame (block-uniform)
            const float Y = y_base + ((float)sy + 0.5f) * bin_h * (1.0f / (float)NSAMP);
            const float X = x_base + ((float)sx + 0.5f) * bin_w * (1.0f / (float)NSAMP);
            float x = X * ct - Y * st + cx;
            float y = X * st + Y * ct + cy;

            const bool valid = !((y < -1.0f) || (y > Hf) || (x < -1.0f) || (x > Wf));
            float yc = fmaxf(y, 0.0f);
            float xc = fmaxf(x, 0.0f);
            int y0 = (int)yc;
            int x0 = (int)xc;
            int y1, x1;
            if (y0 >= H - 1) { y0 = H - 1; y1 = H - 1; yc = (float)y0; }
            else             { y1 = y0 + 1; }
            if (x0 >= W - 1) { x0 = W - 1; x1 = W - 1; xc = (float)x0; }
            else             { x1 = x0 + 1; }

            const float ly = yc - (float)y0, hy = 1.0f - ly;
            const float lx = xc - (float)x0, hx = 1.0f - lx;
            const float vf = valid ? 1.0f : 0.0f;
            const float w1 = hy * hx * vf;
            const float w2 = hy * lx * vf;
            const float w3 = ly * hx * vf;
            const float w4 = ly * lx * vf;

            const float f00 = fbc[y0 * W + x0];
            const float f01 = fbc[y0 * W + x1];
            const float f10 = fbc[y1 * W + x0];
            const float f11 = fbc[y1 * W + x1];
            acc += w1 * f00 + w2 * f01 + w3 * f10 + w4 * f11;
        }
    }
    const float v = acc * 0.25f;   // mean over S*S = 4 samples

    // ---- orientation interpolation via in-wave shuffle ----
    // out channel (cg, o) takes v from channels (cg, (o-ind)%8) and (cg, (o-ind+1)%8)
    const int lane  = threadIdx.x & 63;
    const int base  = lane & ~(NORI - 1);
    const int osrc  = (o - ind + NORI) & (NORI - 1);
    const float v0 = __shfl(v, base | osrc, 64);
    const float v1 = __shfl(v, base | ((osrc + 1) & (NORI - 1)), 64);
    const float result = r_var * v0 + l_var * v1;

    out[((size_t)r * C + c) * (PBIN * PBIN) + ph * PBIN + pw] = result;
}

extern "C" void kernel_launch(void* const* d_in, const int* in_sizes, int n_in,
                              void* d_out, int out_size, void* d_ws, size_t ws_size,
                              hipStream_t stream) {
    const float* feat = (const float*)d_in[0];   // (B, C, H, W) f32
    const float* rois = (const float*)d_in[1];   // (R, 6) f32
    float* out = (float*)d_out;

    const int C = 256, H = 256, W = 256;
    const int R = in_sizes[1] / 6;

    dim3 grid(R * PBIN * PBIN);  // one block per (roi, ph, pw)
    dim3 block(256);             // one thread per channel
    riroi_align_rotated_kernel<<<grid, block, 0, stream>>>(feat, rois, out, C, H, W);
}

// Round 4
// 279.227 us; speedup vs baseline: 2.6331x; 2.6331x over previous
//
#include <hip/hip_runtime.h>

// RiRoIAlignRotated: features (B=2, C=256, H=256, W=256) f32, rois (R=512, 6)
// out (R, C, 7, 7) f32.  C = Cg(32)*O(8), orientation o fastest in channel.
// P = 7, S = 2, SCALE = 0.25, counter-clockwise.
//
// Two-kernel plan:
//   K1: transpose features NCHW -> NHWC into d_ws (fixes gather coalescing;
//       round-3 counters showed FETCH_SIZE 2.0 GB = 15x over-fetch from
//       64-lines-per-wave channel-strided gathers).
//   K2: block = (roi, 64-channel quarter), loops 49 pixels; corner reads are
//       contiguous 256 B wave-loads; results staged in LDS then written as one
//       contiguous 12.5 KB run (fixes WRITE_SIZE 274 MB -> ~26 MB).

#define NORI 8
#define PBIN 7
#define NSAMP 2
#define CCH 256
#define HH 256
#define WW 256
#define PTOT (HH * WW)

// ---------------- K1: NCHW -> NHWC transpose ----------------
// in:  feat[b][c][p]  (p = y*W + x, 65536)
// out: nhwc[b][p][c]
// Tile: 16 positions x 256 channels per block, 256 threads.
__global__ __launch_bounds__(256) void nchw_to_nhwc_kernel(
    const float* __restrict__ feat, float* __restrict__ nhwc)
{
    __shared__ float tile[16][260];          // pitch 260: conflict-light, keeps 16B align
    const int t  = threadIdx.x;
    const int b  = blockIdx.x / (PTOT / 16);
    const int p0 = (blockIdx.x % (PTOT / 16)) * 16;

    // load: float4 along p; per iter 64 channels x 16 B
    const int pl4 = (t & 3) * 4;
    const int cl  = t >> 2;                  // 0..63
    #pragma unroll
    for (int k = 0; k < 4; ++k) {
        const int c = cl + 64 * k;
        const float4 v = *reinterpret_cast<const float4*>(
            feat + ((size_t)b * CCH + c) * PTOT + p0 + pl4);
        tile[pl4 + 0][c] = v.x;
        tile[pl4 + 1][c] = v.y;
        tile[pl4 + 2][c] = v.z;
        tile[pl4 + 3][c] = v.w;
    }
    __syncthreads();

    // store: float4 along c; per wave 1 KB contiguous
    const int c4 = (t & 63) * 4;
    const int plb = t >> 6;                  // 0..3
    #pragma unroll
    for (int k = 0; k < 4; ++k) {
        const int pl = plb + 4 * k;
        float4 v;
        v.x = tile[pl][c4 + 0];
        v.y = tile[pl][c4 + 1];
        v.z = tile[pl][c4 + 2];
        v.w = tile[pl][c4 + 3];
        *reinterpret_cast<float4*>(
            nhwc + ((size_t)b * PTOT + p0 + pl) * CCH + c4) = v;
    }
}

// ---------------- K2: gather from NHWC ----------------
// block = (roi r, channel quarter q): c = q*64 + (t&63); pixel lane = t>>6.
// Each wave handles one pixel at a time (pix wave-uniform) -> orientation
// blend stays an intra-wave shuffle. Results staged in LDS, written as one
// contiguous 64*49-float run.
__global__ __launch_bounds__(256) void riroi_gather_nhwc_kernel(
    const float* __restrict__ nhwc,   // (B, H, W, C)
    const float* __restrict__ rois,   // (R, 6)
    float* __restrict__ out)          // (R, C, 7, 7)
{
    __shared__ float stage[64 * 49];

    const int r  = blockIdx.x >> 2;
    const int q  = blockIdx.x & 3;
    const int t  = threadIdx.x;
    const int cl = t & 63;                 // channel within quarter
    const int c  = q * 64 + cl;
    const int o  = c & (NORI - 1);
    const int pix_base = t >> 6;           // 0..3

    const float* roi = rois + r * 6;
    const int   b     = (int)roi[0];
    const float cx    = roi[1] * 0.25f;
    const float cy    = roi[2] * 0.25f;
    const float rw    = fmaxf(roi[3] * 0.25f, 1.0f);
    const float rh    = fmaxf(roi[4] * 0.25f, 1.0f);
    const float theta = roi[5];

    const float ind_f     = theta * (8.0f / 6.283185307179586f);
    const float ind_floor = floorf(ind_f);
    const float l_var     = ind_f - ind_floor;
    const float r_var     = 1.0f - l_var;
    const int   ind       = (((int)ind_floor % NORI) + NORI) % NORI;

    const float bin_h = rh * (1.0f / (float)PBIN);
    const float bin_w = rw * (1.0f / (float)PBIN);
    const float ct = cosf(theta);
    const float st = sinf(theta);
    const float Hf = (float)HH, Wf = (float)WW;

    const float* __restrict__ fb = nhwc + (size_t)b * PTOT * CCH;

    const int lane = t & 63;
    const int lbase = lane & ~(NORI - 1);
    const int osrc  = (o - ind + NORI) & (NORI - 1);
    const int osrc1 = (osrc + 1) & (NORI - 1);

    for (int pix = pix_base; pix < PBIN * PBIN; pix += 4) {
        const int ph = pix / PBIN;
        const int pw = pix - ph * PBIN;
        const float y_base = -rh * 0.5f + (float)ph * bin_h;
        const float x_base = -rw * 0.5f + (float)pw * bin_w;

        float acc = 0.0f;
        #pragma unroll
        for (int sy = 0; sy < NSAMP; ++sy) {
            #pragma unroll
            for (int sx = 0; sx < NSAMP; ++sx) {
                const float Y = y_base + ((float)sy + 0.5f) * bin_h * 0.5f;
                const float X = x_base + ((float)sx + 0.5f) * bin_w * 0.5f;
                const float x = X * ct - Y * st + cx;
                const float y = X * st + Y * ct + cy;

                const bool valid = !((y < -1.0f) || (y > Hf) || (x < -1.0f) || (x > Wf));
                float yc = fmaxf(y, 0.0f);
                float xc = fmaxf(x, 0.0f);
                int y0 = (int)yc;
                int x0 = (int)xc;
                int y1, x1;
                if (y0 >= HH - 1) { y0 = HH - 1; y1 = HH - 1; yc = (float)y0; }
                else              { y1 = y0 + 1; }
                if (x0 >= WW - 1) { x0 = WW - 1; x1 = WW - 1; xc = (float)x0; }
                else              { x1 = x0 + 1; }

                const float ly = yc - (float)y0, hy = 1.0f - ly;
                const float lx = xc - (float)x0, hx = 1.0f - lx;
                const float vf = valid ? 1.0f : 0.0f;
                const float w1 = hy * hx * vf;
                const float w2 = hy * lx * vf;
                const float w3 = ly * hx * vf;
                const float w4 = ly * lx * vf;

                // NHWC: contiguous 256 B per wave per corner
                const float f00 = fb[((size_t)y0 * WW + x0) * CCH + c];
                const float f01 = fb[((size_t)y0 * WW + x1) * CCH + c];
                const float f10 = fb[((size_t)y1 * WW + x0) * CCH + c];
                const float f11 = fb[((size_t)y1 * WW + x1) * CCH + c];
                acc += w1 * f00 + w2 * f01 + w3 * f10 + w4 * f11;
            }
        }
        const float v = acc * 0.25f;   // mean over 2x2 samples

        // orientation blend (intra-wave: lanes of this wave all hold this pix)
        const float v0 = __shfl(v, lbase | osrc,  64);
        const float v1 = __shfl(v, lbase | osrc1, 64);
        stage[cl * 49 + pix] = r_var * v0 + l_var * v1;
    }
    __syncthreads();

    // contiguous write: 64*49 floats at out + r*12544 + q*3136
    float* __restrict__ dst = out + (size_t)r * (CCH * PBIN * PBIN) + q * (64 * PBIN * PBIN);
    #pragma unroll
    for (int k = 0; k < 13; ++k) {
        const int i = t + 256 * k;
        if (i < 64 * 49) dst[i] = stage[i];
    }
}

// ---------------- fallback (round-3 kernel, used if ws too small) ----------------
__global__ __launch_bounds__(256) void riroi_align_rotated_kernel(
    const float* __restrict__ feat, const float* __restrict__ rois,
    float* __restrict__ out, int C, int H, int W)
{
    const int blk = blockIdx.x;
    const int r   = blk / (PBIN * PBIN);
    const int pix = blk % (PBIN * PBIN);
    const int ph  = pix / PBIN;
    const int pw  = pix % PBIN;
    const int c   = threadIdx.x;
    const int o   = c & (NORI - 1);

    const float* roi = rois + r * 6;
    const int   b     = (int)roi[0];
    const float cx    = roi[1] * 0.25f;
    const float cy    = roi[2] * 0.25f;
    const float rw    = fmaxf(roi[3] * 0.25f, 1.0f);
    const float rh    = fmaxf(roi[4] * 0.25f, 1.0f);
    const float theta = roi[5];

    const float ind_f     = theta * (8.0f / 6.283185307179586f);
    const float ind_floor = floorf(ind_f);
    const float l_var     = ind_f - ind_floor;
    const float r_var     = 1.0f - l_var;
    const int ind = (((int)ind_floor % NORI) + NORI) % NORI;

    const float bin_h = rw * 0.0f + rh * (1.0f / (float)PBIN);
    const float bin_w = rw * (1.0f / (float)PBIN);
    const float ct = cosf(theta);
    const float st = sinf(theta);

    const float* __restrict__ fbc = feat + ((size_t)b * C + c) * (size_t)(H * W);
    const float Hf = (float)H, Wf = (float)W;
    const float y_base = -rh * 0.5f + (float)ph * bin_h;
    const float x_base = -rw * 0.5f + (float)pw * bin_w;

    float acc = 0.0f;
    #pragma unroll
    for (int sy = 0; sy < NSAMP; ++sy) {
        #pragma unroll
        for (int sx = 0; sx < NSAMP; ++sx) {
            const float Y = y_base + ((float)sy + 0.5f) * bin_h * 0.5f;
            const float X = x_base + ((float)sx + 0.5f) * bin_w * 0.5f;
            float x = X * ct - Y * st + cx;
            float y = X * st + Y * ct + cy;
            const bool valid = !((y < -1.0f) || (y > Hf) || (x < -1.0f) || (x > Wf));
            float yc = fmaxf(y, 0.0f);
            float xc = fmaxf(x, 0.0f);
            int y0 = (int)yc;
            int x0 = (int)xc;
            int y1, x1;
            if (y0 >= H - 1) { y0 = H - 1; y1 = H - 1; yc = (float)y0; }
            else             { y1 = y0 + 1; }
            if (x0 >= W - 1) { x0 = W - 1; x1 = W - 1; xc = (float)x0; }
            else             { x1 = x0 + 1; }
            const float ly = yc - (float)y0, hy = 1.0f - ly;
            const float lx = xc - (float)x0, hx = 1.0f - lx;
            const float vf = valid ? 1.0f : 0.0f;
            const float w1 = hy * hx * vf, w2 = hy * lx * vf;
            const float w3 = ly * hx * vf, w4 = ly * lx * vf;
            acc += w1 * fbc[y0 * W + x0] + w2 * fbc[y0 * W + x1]
                 + w3 * fbc[y1 * W + x0] + w4 * fbc[y1 * W + x1];
        }
    }
    const float v = acc * 0.25f;
    const int lane  = threadIdx.x & 63;
    const int base  = lane & ~(NORI - 1);
    const int osrc  = (o - ind + NORI) & (NORI - 1);
    const float v0 = __shfl(v, base | osrc, 64);
    const float v1 = __shfl(v, base | ((osrc + 1) & (NORI - 1)), 64);
    out[((size_t)r * C + c) * (PBIN * PBIN) + ph * PBIN + pw] = r_var * v0 + l_var * v1;
}

extern "C" void kernel_launch(void* const* d_in, const int* in_sizes, int n_in,
                              void* d_out, int out_size, void* d_ws, size_t ws_size,
                              hipStream_t stream) {
    const float* feat = (const float*)d_in[0];   // (B, C, H, W) f32
    const float* rois = (const float*)d_in[1];   // (R, 6) f32
    float* out = (float*)d_out;

    const int R = in_sizes[1] / 6;
    const int B = in_sizes[0] / (CCH * PTOT);
    const size_t need = (size_t)B * PTOT * CCH * sizeof(float);

    if (ws_size >= need) {
        float* nhwc = (float*)d_ws;
        nchw_to_nhwc_kernel<<<dim3(B * (PTOT / 16)), dim3(256), 0, stream>>>(feat, nhwc);
        riroi_gather_nhwc_kernel<<<dim3(R * 4), dim3(256), 0, stream>>>(nhwc, rois, out);
    } else {
        riroi_align_rotated_kernel<<<dim3(R * PBIN * PBIN), dim3(256), 0, stream>>>(
            feat, rois, out, CCH, HH, WW);
    }
}

// Round 5
// 269.788 us; speedup vs baseline: 2.7252x; 1.0350x over previous
//
#include <hip/hip_runtime.h>

// RiRoIAlignRotated: features (B=2, C=256, H=256, W=256) f32, rois (R=512, 6)
// out (R, C, 7, 7) f32.  C = Cg(32)*O(8), o fastest. P=7, S=2, SCALE=0.25, CCW.
//
// K1: NCHW->NHWC transpose, 32p x 128c tiles, register-staged loads
//     (round-4 K1 was latency-bound: VGPR=20 shows serialized load->LDS;
//      16-pos tile used only 64B per 128B line).
// K2: gather from NHWC, one float4 (4 channels) per lane per corner
//     (4x fewer gather instrs); orientation blend via LDS stage.

#define NORI 8
#define PBIN 7
#define NPIX 49
#define CCH 256
#define HH 256
#define WW 256
#define PTOT (HH * WW)

// ---------------- K1: NCHW -> NHWC transpose ----------------
__global__ __launch_bounds__(256) void nchw_to_nhwc_kernel(
    const float* __restrict__ feat, float* __restrict__ nhwc)
{
    __shared__ float tile[32 * 132];     // [p][c] pitch 132 (16B-aligned rows)
    const int t = threadIdx.x;
    int blk = blockIdx.x;
    const int b    = blk >> 12;          // 4096 blocks per batch
    blk &= 4095;
    const int c0   = (blk & 1) * 128;
    const int p0   = (blk >> 1) * 32;

    const float* __restrict__ src = feat + ((size_t)b * CCH + c0) * PTOT + p0;

    // load phase: 4 float4 into regs first (keeps 4 global loads in flight)
    float4 v[4];
    #pragma unroll
    for (int k = 0; k < 4; ++k) {
        const int flat = t + 256 * k;            // 0..1023
        const int c    = flat >> 3;              // 0..127
        const int p4   = (flat & 7) * 4;         // 0..28
        v[k] = *reinterpret_cast<const float4*>(src + (size_t)c * PTOT + p4);
    }
    #pragma unroll
    for (int k = 0; k < 4; ++k) {
        const int flat = t + 256 * k;
        const int c    = flat >> 3;
        const int p4   = (flat & 7) * 4;
        tile[(p4 + 0) * 132 + c] = v[k].x;
        tile[(p4 + 1) * 132 + c] = v[k].y;
        tile[(p4 + 2) * 132 + c] = v[k].z;
        tile[(p4 + 3) * 132 + c] = v[k].w;
    }
    __syncthreads();

    // store phase: b128 LDS reads along c, contiguous 512B global runs
    float* __restrict__ dst = nhwc + ((size_t)b * PTOT + p0) * CCH + c0;
    #pragma unroll
    for (int k = 0; k < 4; ++k) {
        const int flat = t + 256 * k;
        const int p    = flat >> 5;              // 0..31
        const int cg4  = (flat & 31) * 4;        // 0..124
        float4 w;
        w.x = tile[p * 132 + cg4 + 0];
        w.y = tile[p * 132 + cg4 + 1];
        w.z = tile[p * 132 + cg4 + 2];
        w.w = tile[p * 132 + cg4 + 3];
        *reinterpret_cast<float4*>(dst + (size_t)p * CCH + cg4) = w;
    }
}

// ---------------- K2: gather from NHWC ----------------
// block = (roi r, 64-channel quarter q). lane: cl4=(t&15)*4 channels, pixel
// group t>>4 (16 pixel lanes). Corner loads are float4 (b128), 16 lanes x 16B
// contiguous per pixel. v staged in LDS; blend+write phase reads the two
// source channels per output (ind block-uniform) and writes one contiguous
// 12.5 KB run.
__global__ __launch_bounds__(256) void riroi_gather_nhwc_kernel(
    const float* __restrict__ nhwc,   // (B, H, W, C)
    const float* __restrict__ rois,   // (R, 6)
    float* __restrict__ out)          // (R, C, 7, 7)
{
    __shared__ float stage[64 * NPIX];   // [c_local][pix]

    const int r   = blockIdx.x >> 2;
    const int q   = blockIdx.x & 3;
    const int t   = threadIdx.x;
    const int cl4 = (t & 15) * 4;        // local channel base 0..60
    const int c4  = q * 64 + cl4;        // global channel base
    const int pixlane = t >> 4;          // 0..15

    const float* roi = rois + r * 6;
    const int   b     = (int)roi[0];
    const float cx    = roi[1] * 0.25f;
    const float cy    = roi[2] * 0.25f;
    const float rw    = fmaxf(roi[3] * 0.25f, 1.0f);
    const float rh    = fmaxf(roi[4] * 0.25f, 1.0f);
    const float theta = roi[5];

    const float ind_f     = theta * (8.0f / 6.283185307179586f);
    const float ind_floor = floorf(ind_f);
    const float l_var     = ind_f - ind_floor;
    const float r_var     = 1.0f - l_var;
    const int   ind       = (((int)ind_floor % NORI) + NORI) % NORI;

    const float bin_h = rh * (1.0f / (float)PBIN);
    const float bin_w = rw * (1.0f / (float)PBIN);
    const float ct = cosf(theta);
    const float st = sinf(theta);
    const float Hf = (float)HH, Wf = (float)WW;

    const float* __restrict__ fb = nhwc + (size_t)b * PTOT * CCH;

    #pragma unroll
    for (int k = 0; k < 4; ++k) {
        const int pix = pixlane + 16 * k;
        if (pix < NPIX) {
            const int ph = pix / PBIN;
            const int pw = pix - ph * PBIN;
            const float y_base = -rh * 0.5f + (float)ph * bin_h;
            const float x_base = -rw * 0.5f + (float)pw * bin_w;

            float ax = 0.0f, ay = 0.0f, az = 0.0f, aw = 0.0f;
            #pragma unroll
            for (int sy = 0; sy < 2; ++sy) {
                #pragma unroll
                for (int sx = 0; sx < 2; ++sx) {
                    const float Y = y_base + ((float)sy + 0.5f) * bin_h * 0.5f;
                    const float X = x_base + ((float)sx + 0.5f) * bin_w * 0.5f;
                    const float x = X * ct - Y * st + cx;
                    const float y = X * st + Y * ct + cy;

                    const bool valid = !((y < -1.0f) || (y > Hf) || (x < -1.0f) || (x > Wf));
                    float yc = fmaxf(y, 0.0f);
                    float xc = fmaxf(x, 0.0f);
                    int y0 = (int)yc;
                    int x0 = (int)xc;
                    int y1, x1;
                    if (y0 >= HH - 1) { y0 = HH - 1; y1 = HH - 1; yc = (float)y0; }
                    else              { y1 = y0 + 1; }
                    if (x0 >= WW - 1) { x0 = WW - 1; x1 = WW - 1; xc = (float)x0; }
                    else              { x1 = x0 + 1; }

                    const float ly = yc - (float)y0, hy = 1.0f - ly;
                    const float lx = xc - (float)x0, hx = 1.0f - lx;
                    const float vf = valid ? 1.0f : 0.0f;
                    const float w1 = hy * hx * vf;
                    const float w2 = hy * lx * vf;
                    const float w3 = ly * hx * vf;
                    const float w4 = ly * lx * vf;

                    const float4 f00 = *reinterpret_cast<const float4*>(
                        fb + ((size_t)(y0 * WW + x0)) * CCH + c4);
                    const float4 f01 = *reinterpret_cast<const float4*>(
                        fb + ((size_t)(y0 * WW + x1)) * CCH + c4);
                    const float4 f10 = *reinterpret_cast<const float4*>(
                        fb + ((size_t)(y1 * WW + x0)) * CCH + c4);
                    const float4 f11 = *reinterpret_cast<const float4*>(
                        fb + ((size_t)(y1 * WW + x1)) * CCH + c4);

                    ax += w1 * f00.x + w2 * f01.x + w3 * f10.x + w4 * f11.x;
                    ay += w1 * f00.y + w2 * f01.y + w3 * f10.y + w4 * f11.y;
                    az += w1 * f00.z + w2 * f01.z + w3 * f10.z + w4 * f11.z;
                    aw += w1 * f00.w + w2 * f01.w + w3 * f10.w + w4 * f11.w;
                }
            }
            stage[(cl4 + 0) * NPIX + pix] = ax * 0.25f;
            stage[(cl4 + 1) * NPIX + pix] = ay * 0.25f;
            stage[(cl4 + 2) * NPIX + pix] = az * 0.25f;
            stage[(cl4 + 3) * NPIX + pix] = aw * 0.25f;
        }
    }
    __syncthreads();

    // blend orientations + contiguous write of 64*49 floats
    float* __restrict__ dst = out + (size_t)r * (CCH * NPIX) + q * (64 * NPIX);
    #pragma unroll
    for (int k = 0; k < 13; ++k) {
        const int i = t + 256 * k;
        if (i < 64 * NPIX) {
            const int c   = i / NPIX;            // local out channel 0..63
            const int pix = i - c * NPIX;
            const int o   = c & (NORI - 1);
            const int s0  = (c & ~(NORI - 1)) | ((o - ind + 8) & (NORI - 1));
            const int s1  = (c & ~(NORI - 1)) | ((o - ind + 9) & (NORI - 1));
            dst[i] = r_var * stage[s0 * NPIX + pix] + l_var * stage[s1 * NPIX + pix];
        }
    }
}

// ---------------- fallback (validated round-3 kernel) ----------------
__global__ __launch_bounds__(256) void riroi_align_rotated_kernel(
    const float* __restrict__ feat, const float* __restrict__ rois,
    float* __restrict__ out, int C, int H, int W)
{
    const int blk = blockIdx.x;
    const int r   = blk / (PBIN * PBIN);
    const int pix = blk % (PBIN * PBIN);
    const int ph  = pix / PBIN;
    const int pw  = pix % PBIN;
    const int c   = threadIdx.x;
    const int o   = c & (NORI - 1);

    const float* roi = rois + r * 6;
    const int   b     = (int)roi[0];
    const float cx    = roi[1] * 0.25f;
    const float cy    = roi[2] * 0.25f;
    const float rw    = fmaxf(roi[3] * 0.25f, 1.0f);
    const float rh    = fmaxf(roi[4] * 0.25f, 1.0f);
    const float theta = roi[5];

    const float ind_f     = theta * (8.0f / 6.283185307179586f);
    const float ind_floor = floorf(ind_f);
    const float l_var     = ind_f - ind_floor;
    const float r_var     = 1.0f - l_var;
    const int ind = (((int)ind_floor % NORI) + NORI) % NORI;

    const float bin_h = rh * (1.0f / (float)PBIN);
    const float bin_w = rw * (1.0f / (float)PBIN);
    const float ct = cosf(theta);
    const float st = sinf(theta);

    const float* __restrict__ fbc = feat + ((size_t)b * C + c) * (size_t)(H * W);
    const float Hf = (float)H, Wf = (float)W;
    const float y_base = -rh * 0.5f + (float)ph * bin_h;
    const float x_base = -rw * 0.5f + (float)pw * bin_w;

    float acc = 0.0f;
    #pragma unroll
    for (int sy = 0; sy < 2; ++sy) {
        #pragma unroll
        for (int sx = 0; sx < 2; ++sx) {
            const float Y = y_base + ((float)sy + 0.5f) * bin_h * 0.5f;
            const float X = x_base + ((float)sx + 0.5f) * bin_w * 0.5f;
            float x = X * ct - Y * st + cx;
            float y = X * st + Y * ct + cy;
            const bool valid = !((y < -1.0f) || (y > Hf) || (x < -1.0f) || (x > Wf));
            float yc = fmaxf(y, 0.0f);
            float xc = fmaxf(x, 0.0f);
            int y0 = (int)yc;
            int x0 = (int)xc;
            int y1, x1;
            if (y0 >= H - 1) { y0 = H - 1; y1 = H - 1; yc = (float)y0; }
            else             { y1 = y0 + 1; }
            if (x0 >= W - 1) { x0 = W - 1; x1 = W - 1; xc = (float)x0; }
            else             { x1 = x0 + 1; }
            const float ly = yc - (float)y0, hy = 1.0f - ly;
            const float lx = xc - (float)x0, hx = 1.0f - lx;
            const float vf = valid ? 1.0f : 0.0f;
            const float w1 = hy * hx * vf, w2 = hy * lx * vf;
            const float w3 = ly * hx * vf, w4 = ly * lx * vf;
            acc += w1 * fbc[y0 * W + x0] + w2 * fbc[y0 * W + x1]
                 + w3 * fbc[y1 * W + x0] + w4 * fbc[y1 * W + x1];
        }
    }
    const float v = acc * 0.25f;
    const int lane  = threadIdx.x & 63;
    const int base  = lane & ~(NORI - 1);
    const int osrc  = (o - ind + NORI) & (NORI - 1);
    const float v0 = __shfl(v, base | osrc, 64);
    const float v1 = __shfl(v, base | ((osrc + 1) & (NORI - 1)), 64);
    out[((size_t)r * C + c) * (PBIN * PBIN) + ph * PBIN + pw] = r_var * v0 + l_var * v1;
}

extern "C" void kernel_launch(void* const* d_in, const int* in_sizes, int n_in,
                              void* d_out, int out_size, void* d_ws, size_t ws_size,
                              hipStream_t stream) {
    const float* feat = (const float*)d_in[0];   // (B, C, H, W) f32
    const float* rois = (const float*)d_in[1];   // (R, 6) f32
    float* out = (float*)d_out;

    const int R = in_sizes[1] / 6;
    const int B = in_sizes[0] / (CCH * PTOT);
    const size_t need = (size_t)B * PTOT * CCH * sizeof(float);

    if (ws_size >= need) {
        float* nhwc = (float*)d_ws;
        nchw_to_nhwc_kernel<<<dim3(B * 4096), dim3(256), 0, stream>>>(feat, nhwc);
        riroi_gather_nhwc_kernel<<<dim3(R * 4), dim3(256), 0, stream>>>(nhwc, rois, out);
    } else {
        riroi_align_rotated_kernel<<<dim3(R * PBIN * PBIN), dim3(256), 0, stream>>>(
            feat, rois, out, CCH, HH, WW);
    }
}

// Round 6
// 267.946 us; speedup vs baseline: 2.7439x; 1.0069x over previous
//
#include <hip/hip_runtime.h>

// RiRoIAlignRotated: features (B=2, C=256, H=256, W=256) f32, rois (R=512, 6)
// out (R, C, 7, 7) f32.  C = Cg(32)*O(8), o fastest. P=7, S=2, SCALE=0.25, CCW.
//
// K1 v3: NCHW->NHWC. b32 loads with lanes along p (256 B runs), lane packs 4
//   channels -> ds_write_b128 along c. Tile [128p][64c] pitch 68 (68%32==4:
//   p enters bank bits; all LDS phases <=2-way). Round-5 K1 had 4-way scatter
//   conflicts (pitch 132, 4-row scalar scatter) + 128 B-granule reads.
// K2: gather from NHWC (unchanged from round 5, ~50 us).

#define NORI 8
#define PBIN 7
#define NPIX 49
#define CCH 256
#define HH 256
#define WW 256
#define PTOT (HH * WW)

// ---------------- K1: NCHW -> NHWC transpose ----------------
__global__ __launch_bounds__(256) void nchw_to_nhwc_kernel(
    const float* __restrict__ feat, float* __restrict__ nhwc)
{
    __shared__ float tile[128 * 68];      // [p_local][c_local], pitch 68
    const int t = threadIdx.x;
    int blk = blockIdx.x;
    const int b  = blk >> 11;             // 2048 blocks per batch
    blk &= 2047;
    const int p0 = (blk >> 2) * 128;      // 512 p-tiles
    const int c0 = (blk & 3) * 64;        // 4 c-tiles

    const int pl    = t & 127;            // local p (lanes consecutive in p)
    const int chalf = (t >> 7) * 4;       // 0 or 4

    const float* __restrict__ src = feat + ((size_t)b * CCH + c0) * PTOT + p0 + pl;

    // 8 x { 4 coalesced b32 loads (4 channels, same p) -> 1 ds_write_b128 }
    #pragma unroll
    for (int k = 0; k < 8; ++k) {
        const int cl = chalf + 8 * k;     // 0..60, 4-aligned
        float4 v;
        v.x = src[(size_t)(cl + 0) * PTOT];
        v.y = src[(size_t)(cl + 1) * PTOT];
        v.z = src[(size_t)(cl + 2) * PTOT];
        v.w = src[(size_t)(cl + 3) * PTOT];
        *reinterpret_cast<float4*>(&tile[pl * 68 + cl]) = v;
    }
    __syncthreads();

    // 8 x { 1 ds_read_b128 -> 1 coalesced dwordx4 store (256 B runs along c) }
    float* __restrict__ dst = nhwc + ((size_t)b * PTOT + p0) * CCH + c0;
    #pragma unroll
    for (int k = 0; k < 8; ++k) {
        const int flat = t + 256 * k;     // 0..2047
        const int p    = flat >> 4;       // 0..127
        const int c4   = (flat & 15) * 4; // 0..60
        const float4 w = *reinterpret_cast<const float4*>(&tile[p * 68 + c4]);
        *reinterpret_cast<float4*>(dst + (size_t)p * CCH + c4) = w;
    }
}

// ---------------- K2: gather from NHWC (unchanged) ----------------
__global__ __launch_bounds__(256) void riroi_gather_nhwc_kernel(
    const float* __restrict__ nhwc,   // (B, H, W, C)
    const float* __restrict__ rois,   // (R, 6)
    float* __restrict__ out)          // (R, C, 7, 7)
{
    __shared__ float stage[64 * NPIX];   // [c_local][pix]

    const int r   = blockIdx.x >> 2;
    const int q   = blockIdx.x & 3;
    const int t   = threadIdx.x;
    const int cl4 = (t & 15) * 4;        // local channel base 0..60
    const int c4  = q * 64 + cl4;        // global channel base
    const int pixlane = t >> 4;          // 0..15

    const float* roi = rois + r * 6;
    const int   b     = (int)roi[0];
    const float cx    = roi[1] * 0.25f;
    const float cy    = roi[2] * 0.25f;
    const float rw    = fmaxf(roi[3] * 0.25f, 1.0f);
    const float rh    = fmaxf(roi[4] * 0.25f, 1.0f);
    const float theta = roi[5];

    const float ind_f     = theta * (8.0f / 6.283185307179586f);
    const float ind_floor = floorf(ind_f);
    const float l_var     = ind_f - ind_floor;
    const float r_var     = 1.0f - l_var;
    const int   ind       = (((int)ind_floor % NORI) + NORI) % NORI;

    const float bin_h = rh * (1.0f / (float)PBIN);
    const float bin_w = rw * (1.0f / (float)PBIN);
    const float ct = cosf(theta);
    const float st = sinf(theta);
    const float Hf = (float)HH, Wf = (float)WW;

    const float* __restrict__ fb = nhwc + (size_t)b * PTOT * CCH;

    #pragma unroll
    for (int k = 0; k < 4; ++k) {
        const int pix = pixlane + 16 * k;
        if (pix < NPIX) {
            const int ph = pix / PBIN;
            const int pw = pix - ph * PBIN;
            const float y_base = -rh * 0.5f + (float)ph * bin_h;
            const float x_base = -rw * 0.5f + (float)pw * bin_w;

            float ax = 0.0f, ay = 0.0f, az = 0.0f, aw = 0.0f;
            #pragma unroll
            for (int sy = 0; sy < 2; ++sy) {
                #pragma unroll
                for (int sx = 0; sx < 2; ++sx) {
                    const float Y = y_base + ((float)sy + 0.5f) * bin_h * 0.5f;
                    const float X = x_base + ((float)sx + 0.5f) * bin_w * 0.5f;
                    const float x = X * ct - Y * st + cx;
                    const float y = X * st + Y * ct + cy;

                    const bool valid = !((y < -1.0f) || (y > Hf) || (x < -1.0f) || (x > Wf));
                    float yc = fmaxf(y, 0.0f);
                    float xc = fmaxf(x, 0.0f);
                    int y0 = (int)yc;
                    int x0 = (int)xc;
                    int y1, x1;
                    if (y0 >= HH - 1) { y0 = HH - 1; y1 = HH - 1; yc = (float)y0; }
                    else              { y1 = y0 + 1; }
                    if (x0 >= WW - 1) { x0 = WW - 1; x1 = WW - 1; xc = (float)x0; }
                    else              { x1 = x0 + 1; }

                    const float ly = yc - (float)y0, hy = 1.0f - ly;
                    const float lx = xc - (float)x0, hx = 1.0f - lx;
                    const float vf = valid ? 1.0f : 0.0f;
                    const float w1 = hy * hx * vf;
                    const float w2 = hy * lx * vf;
                    const float w3 = ly * hx * vf;
                    const float w4 = ly * lx * vf;

                    const float4 f00 = *reinterpret_cast<const float4*>(
                        fb + ((size_t)(y0 * WW + x0)) * CCH + c4);
                    const float4 f01 = *reinterpret_cast<const float4*>(
                        fb + ((size_t)(y0 * WW + x1)) * CCH + c4);
                    const float4 f10 = *reinterpret_cast<const float4*>(
                        fb + ((size_t)(y1 * WW + x0)) * CCH + c4);
                    const float4 f11 = *reinterpret_cast<const float4*>(
                        fb + ((size_t)(y1 * WW + x1)) * CCH + c4);

                    ax += w1 * f00.x + w2 * f01.x + w3 * f10.x + w4 * f11.x;
                    ay += w1 * f00.y + w2 * f01.y + w3 * f10.y + w4 * f11.y;
                    az += w1 * f00.z + w2 * f01.z + w3 * f10.z + w4 * f11.z;
                    aw += w1 * f00.w + w2 * f01.w + w3 * f10.w + w4 * f11.w;
                }
            }
            stage[(cl4 + 0) * NPIX + pix] = ax * 0.25f;
            stage[(cl4 + 1) * NPIX + pix] = ay * 0.25f;
            stage[(cl4 + 2) * NPIX + pix] = az * 0.25f;
            stage[(cl4 + 3) * NPIX + pix] = aw * 0.25f;
        }
    }
    __syncthreads();

    // blend orientations + contiguous write of 64*49 floats
    float* __restrict__ dst = out + (size_t)r * (CCH * NPIX) + q * (64 * NPIX);
    #pragma unroll
    for (int k = 0; k < 13; ++k) {
        const int i = t + 256 * k;
        if (i < 64 * NPIX) {
            const int c   = i / NPIX;            // local out channel 0..63
            const int pix = i - c * NPIX;
            const int o   = c & (NORI - 1);
            const int s0  = (c & ~(NORI - 1)) | ((o - ind + 8) & (NORI - 1));
            const int s1  = (c & ~(NORI - 1)) | ((o - ind + 9) & (NORI - 1));
            dst[i] = r_var * stage[s0 * NPIX + pix] + l_var * stage[s1 * NPIX + pix];
        }
    }
}

// ---------------- fallback (validated round-3 kernel) ----------------
__global__ __launch_bounds__(256) void riroi_align_rotated_kernel(
    const float* __restrict__ feat, const float* __restrict__ rois,
    float* __restrict__ out, int C, int H, int W)
{
    const int blk = blockIdx.x;
    const int r   = blk / (PBIN * PBIN);
    const int pix = blk % (PBIN * PBIN);
    const int ph  = pix / PBIN;
    const int pw  = pix % PBIN;
    const int c   = threadIdx.x;
    const int o   = c & (NORI - 1);

    const float* roi = rois + r * 6;
    const int   b     = (int)roi[0];
    const float cx    = roi[1] * 0.25f;
    const float cy    = roi[2] * 0.25f;
    const float rw    = fmaxf(roi[3] * 0.25f, 1.0f);
    const float rh    = fmaxf(roi[4] * 0.25f, 1.0f);
    const float theta = roi[5];

    const float ind_f     = theta * (8.0f / 6.283185307179586f);
    const float ind_floor = floorf(ind_f);
    const float l_var     = ind_f - ind_floor;
    const float r_var     = 1.0f - l_var;
    const int ind = (((int)ind_floor % NORI) + NORI) % NORI;

    const float bin_h = rh * (1.0f / (float)PBIN);
    const float bin_w = rw * (1.0f / (float)PBIN);
    const float ct = cosf(theta);
    const float st = sinf(theta);

    const float* __restrict__ fbc = feat + ((size_t)b * C + c) * (size_t)(H * W);
    const float Hf = (float)H, Wf = (float)W;
    const float y_base = -rh * 0.5f + (float)ph * bin_h;
    const float x_base = -rw * 0.5f + (float)pw * bin_w;

    float acc = 0.0f;
    #pragma unroll
    for (int sy = 0; sy < 2; ++sy) {
        #pragma unroll
        for (int sx = 0; sx < 2; ++sx) {
            const float Y = y_base + ((float)sy + 0.5f) * bin_h * 0.5f;
            const float X = x_base + ((float)sx + 0.5f) * bin_w * 0.5f;
            float x = X * ct - Y * st + cx;
            float y = X * st + Y * ct + cy;
            const bool valid = !((y < -1.0f) || (y > Hf) || (x < -1.0f) || (x > Wf));
            float yc = fmaxf(y, 0.0f);
            float xc = fmaxf(x, 0.0f);
            int y0 = (int)yc;
            int x0 = (int)xc;
            int y1, x1;
            if (y0 >= H - 1) { y0 = H - 1; y1 = H - 1; yc = (float)y0; }
            else             { y1 = y0 + 1; }
            if (x0 >= W - 1) { x0 = W - 1; x1 = W - 1; xc = (float)x0; }
            else             { x1 = x0 + 1; }
            const float ly = yc - (float)y0, hy = 1.0f - ly;
            const float lx = xc - (float)x0, hx = 1.0f - lx;
            const float vf = valid ? 1.0f : 0.0f;
            const float w1 = hy * hx * vf, w2 = hy * lx * vf;
            const float w3 = ly * hx * vf, w4 = ly * lx * vf;
            acc += w1 * fbc[y0 * W + x0] + w2 * fbc[y0 * W + x1]
                 + w3 * fbc[y1 * W + x0] + w4 * fbc[y1 * W + x1];
        }
    }
    const float v = acc * 0.25f;
    const int lane  = threadIdx.x & 63;
    const int base  = lane & ~(NORI - 1);
    const int osrc  = (o - ind + NORI) & (NORI - 1);
    const float v0 = __shfl(v, base | osrc, 64);
    const float v1 = __shfl(v, base | ((osrc + 1) & (NORI - 1)), 64);
    out[((size_t)r * C + c) * (PBIN * PBIN) + ph * PBIN + pw] = r_var * v0 + l_var * v1;
}

extern "C" void kernel_launch(void* const* d_in, const int* in_sizes, int n_in,
                              void* d_out, int out_size, void* d_ws, size_t ws_size,
                              hipStream_t stream) {
    const float* feat = (const float*)d_in[0];   // (B, C, H, W) f32
    const float* rois = (const float*)d_in[1];   // (R, 6) f32
    float* out = (float*)d_out;

    const int R = in_sizes[1] / 6;
    const int B = in_sizes[0] / (CCH * PTOT);
    const size_t need = (size_t)B * PTOT * CCH * sizeof(float);

    if (ws_size >= need) {
        float* nhwc = (float*)d_ws;
        nchw_to_nhwc_kernel<<<dim3(B * 2048), dim3(256), 0, stream>>>(feat, nhwc);
        riroi_gather_nhwc_kernel<<<dim3(R * 4), dim3(256), 0, stream>>>(nhwc, rois, out);
    } else {
        riroi_align_rotated_kernel<<<dim3(R * PBIN * PBIN), dim3(256), 0, stream>>>(
            feat, rois, out, CCH, HH, WW);
    }
}

// Round 7
// 266.596 us; speedup vs baseline: 2.7578x; 1.0051x over previous
//
#include <hip/hip_runtime.h>

// RiRoIAlignRotated: features (B=2, C=256, H=256, W=256) f32, rois (R=512, 6)
// out (R, C, 7, 7) f32.  C = Cg(32)*O(8), o fastest. P=7, S=2, SCALE=0.25, CCW.
//
// K1 v4: NCHW->NHWC, 128c x 128p tile (64 KB LDS = static max, 2 blocks/CU).
//   Reads: per channel 2 back-to-back 256 B runs (512 B sequential per visit).
//   4x4 register transpose (__shfl_xor butterfly) -> ds_write_b128 c-major,
//   XOR bank-quad swizzle (cq ^ (p&7)) => both LDS phases conflict-free.
//   Writes: 512 B contiguous per p-row per instr.
//   (Rounds 4-6: three K1 variants all ~83-89 us @ ~2.4 TB/s; theory = short
//    strided runs (<=512B reads / 256B cross-XCD write fragments) derate DRAM.)
// K2: gather from NHWC (unchanged, ~50 us).

#define NORI 8
#define PBIN 7
#define NPIX 49
#define CCH 256
#define HH 256
#define WW 256
#define PTOT (HH * WW)

// ---------------- K1: NCHW -> NHWC transpose ----------------
__global__ __launch_bounds__(256) void nchw_to_nhwc_kernel(
    const float* __restrict__ feat, float* __restrict__ nhwc)
{
    // [128 p][32 cq] of 16B units, cq swizzled by p&7  => 65536 B exactly
    __shared__ float tile[128 * 128];

    const int t = threadIdx.x;
    const int l = t & 63;                 // lane
    const int w = t >> 6;                 // wave 0..3
    const int blk = blockIdx.x;
    const int b  = blk >> 10;             // 1024 blocks per batch
    const int rest = blk & 1023;
    const int p0 = (rest >> 1) << 7;      // 512 p-tiles * 128
    const int c0 = (rest & 1) << 7;       // 2 c-tiles * 128

    const int cb = c0 + 32 * w;           // this wave's 32 channels

    // ---- phase A: load 16 float4 (all independent, kept in flight) ----
    // lane l: c = cb + 4k + (l&3), p = p0 + 64h + 4*(l>>2) .. +3
    float4 v[16];
    #pragma unroll
    for (int k = 0; k < 8; ++k) {
        #pragma unroll
        for (int h = 0; h < 2; ++h) {
            const int c  = cb + 4 * k + (l & 3);
            const int p  = p0 + 64 * h + 4 * (l >> 2);
            v[k * 2 + h] = *reinterpret_cast<const float4*>(
                feat + ((size_t)b * CCH + c) * PTOT + p);
        }
    }

    // ---- 4x4 register transpose within lane quads + b128 LDS write ----
    #pragma unroll
    for (int k = 0; k < 8; ++k) {
        #pragma unroll
        for (int h = 0; h < 2; ++h) {
            float4 a = v[k * 2 + h];
            // stage 1: xor 1
            {
                const float e0 = (l & 1) ? a.x : a.y;
                const float e1 = (l & 1) ? a.z : a.w;
                const float r0 = __shfl_xor(e0, 1, 64);
                const float r1 = __shfl_xor(e1, 1, 64);
                if (l & 1) { a.x = r0; a.z = r1; } else { a.y = r0; a.w = r1; }
            }
            // stage 2: xor 2
            {
                const float f0 = (l & 2) ? a.x : a.z;
                const float f1 = (l & 2) ? a.y : a.w;
                const float s0 = __shfl_xor(f0, 2, 64);
                const float s1 = __shfl_xor(f1, 2, 64);
                if (l & 2) { a.x = s0; a.y = s1; } else { a.z = s0; a.w = s1; }
            }
            // lane l now holds channels cb+4k..+3 at p_local = 64h + l
            const int p_local = 64 * h + l;
            const int cq = 8 * w + k;                  // 16B-unit column 0..31
            const int cqs = cq ^ (p_local & 7);        // bank-quad swizzle
            *reinterpret_cast<float4*>(&tile[p_local * 128 + cqs * 4]) = a;
        }
    }
    __syncthreads();

    // ---- phase B: b128 LDS read + 512 B-contiguous global stores ----
    float* __restrict__ dst = nhwc + ((size_t)b * PTOT + p0) * CCH + c0;
    #pragma unroll
    for (int j = 0; j < 16; ++j) {
        const int flat = t + 256 * j;     // 0..4095
        const int p    = flat >> 5;       // 0..127
        const int cq   = flat & 31;       // 0..31
        const int cqs  = cq ^ (p & 7);
        const float4 a = *reinterpret_cast<const float4*>(&tile[p * 128 + cqs * 4]);
        *reinterpret_cast<float4*>(dst + (size_t)p * CCH + cq * 4) = a;
    }
}

// ---------------- K2: gather from NHWC (unchanged) ----------------
__global__ __launch_bounds__(256) void riroi_gather_nhwc_kernel(
    const float* __restrict__ nhwc,   // (B, H, W, C)
    const float* __restrict__ rois,   // (R, 6)
    float* __restrict__ out)          // (R, C, 7, 7)
{
    __shared__ float stage[64 * NPIX];   // [c_local][pix]

    const int r   = blockIdx.x >> 2;
    const int q   = blockIdx.x & 3;
    const int t   = threadIdx.x;
    const int cl4 = (t & 15) * 4;        // local channel base 0..60
    const int c4  = q * 64 + cl4;        // global channel base
    const int pixlane = t >> 4;          // 0..15

    const float* roi = rois + r * 6;
    const int   b     = (int)roi[0];
    const float cx    = roi[1] * 0.25f;
    const float cy    = roi[2] * 0.25f;
    const float rw    = fmaxf(roi[3] * 0.25f, 1.0f);
    const float rh    = fmaxf(roi[4] * 0.25f, 1.0f);
    const float theta = roi[5];

    const float ind_f     = theta * (8.0f / 6.283185307179586f);
    const float ind_floor = floorf(ind_f);
    const float l_var     = ind_f - ind_floor;
    const float r_var     = 1.0f - l_var;
    const int   ind       = (((int)ind_floor % NORI) + NORI) % NORI;

    const float bin_h = rh * (1.0f / (float)PBIN);
    const float bin_w = rw * (1.0f / (float)PBIN);
    const float ct = cosf(theta);
    const float st = sinf(theta);
    const float Hf = (float)HH, Wf = (float)WW;

    const float* __restrict__ fb = nhwc + (size_t)b * PTOT * CCH;

    #pragma unroll
    for (int k = 0; k < 4; ++k) {
        const int pix = pixlane + 16 * k;
        if (pix < NPIX) {
            const int ph = pix / PBIN;
            const int pw = pix - ph * PBIN;
            const float y_base = -rh * 0.5f + (float)ph * bin_h;
            const float x_base = -rw * 0.5f + (float)pw * bin_w;

            float ax = 0.0f, ay = 0.0f, az = 0.0f, aw = 0.0f;
            #pragma unroll
            for (int sy = 0; sy < 2; ++sy) {
                #pragma unroll
                for (int sx = 0; sx < 2; ++sx) {
                    const float Y = y_base + ((float)sy + 0.5f) * bin_h * 0.5f;
                    const float X = x_base + ((float)sx + 0.5f) * bin_w * 0.5f;
                    const float x = X * ct - Y * st + cx;
                    const float y = X * st + Y * ct + cy;

                    const bool valid = !((y < -1.0f) || (y > Hf) || (x < -1.0f) || (x > Wf));
                    float yc = fmaxf(y, 0.0f);
                    float xc = fmaxf(x, 0.0f);
                    int y0 = (int)yc;
                    int x0 = (int)xc;
                    int y1, x1;
                    if (y0 >= HH - 1) { y0 = HH - 1; y1 = HH - 1; yc = (float)y0; }
                    else              { y1 = y0 + 1; }
                    if (x0 >= WW - 1) { x0 = WW - 1; x1 = WW - 1; xc = (float)x0; }
                    else              { x1 = x0 + 1; }

                    const float ly = yc - (float)y0, hy = 1.0f - ly;
                    const float lx = xc - (float)x0, hx = 1.0f - lx;
                    const float vf = valid ? 1.0f : 0.0f;
                    const float w1 = hy * hx * vf;
                    const float w2 = hy * lx * vf;
                    const float w3 = ly * hx * vf;
                    const float w4 = ly * lx * vf;

                    const float4 f00 = *reinterpret_cast<const float4*>(
                        fb + ((size_t)(y0 * WW + x0)) * CCH + c4);
                    const float4 f01 = *reinterpret_cast<const float4*>(
                        fb + ((size_t)(y0 * WW + x1)) * CCH + c4);
                    const float4 f10 = *reinterpret_cast<const float4*>(
                        fb + ((size_t)(y1 * WW + x0)) * CCH + c4);
                    const float4 f11 = *reinterpret_cast<const float4*>(
                        fb + ((size_t)(y1 * WW + x1)) * CCH + c4);

                    ax += w1 * f00.x + w2 * f01.x + w3 * f10.x + w4 * f11.x;
                    ay += w1 * f00.y + w2 * f01.y + w3 * f10.y + w4 * f11.y;
                    az += w1 * f00.z + w2 * f01.z + w3 * f10.z + w4 * f11.z;
                    aw += w1 * f00.w + w2 * f01.w + w3 * f10.w + w4 * f11.w;
                }
            }
            stage[(cl4 + 0) * NPIX + pix] = ax * 0.25f;
            stage[(cl4 + 1) * NPIX + pix] = ay * 0.25f;
            stage[(cl4 + 2) * NPIX + pix] = az * 0.25f;
            stage[(cl4 + 3) * NPIX + pix] = aw * 0.25f;
        }
    }
    __syncthreads();

    // blend orientations + contiguous write of 64*49 floats
    float* __restrict__ dst = out + (size_t)r * (CCH * NPIX) + q * (64 * NPIX);
    #pragma unroll
    for (int k = 0; k < 13; ++k) {
        const int i = t + 256 * k;
        if (i < 64 * NPIX) {
            const int c   = i / NPIX;            // local out channel 0..63
            const int pix = i - c * NPIX;
            const int o   = c & (NORI - 1);
            const int s0  = (c & ~(NORI - 1)) | ((o - ind + 8) & (NORI - 1));
            const int s1  = (c & ~(NORI - 1)) | ((o - ind + 9) & (NORI - 1));
            dst[i] = r_var * stage[s0 * NPIX + pix] + l_var * stage[s1 * NPIX + pix];
        }
    }
}

// ---------------- fallback (validated round-3 kernel) ----------------
__global__ __launch_bounds__(256) void riroi_align_rotated_kernel(
    const float* __restrict__ feat, const float* __restrict__ rois,
    float* __restrict__ out, int C, int H, int W)
{
    const int blk = blockIdx.x;
    const int r   = blk / (PBIN * PBIN);
    const int pix = blk % (PBIN * PBIN);
    const int ph  = pix / PBIN;
    const int pw  = pix % PBIN;
    const int c   = threadIdx.x;
    const int o   = c & (NORI - 1);

    const float* roi = rois + r * 6;
    const int   b     = (int)roi[0];
    const float cx    = roi[1] * 0.25f;
    const float cy    = roi[2] * 0.25f;
    const float rw    = fmaxf(roi[3] * 0.25f, 1.0f);
    const float rh    = fmaxf(roi[4] * 0.25f, 1.0f);
    const float theta = roi[5];

    const float ind_f     = theta * (8.0f / 6.283185307179586f);
    const float ind_floor = floorf(ind_f);
    const float l_var     = ind_f - ind_floor;
    const float r_var     = 1.0f - l_var;
    const int ind = (((int)ind_floor % NORI) + NORI) % NORI;

    const float bin_h = rh * (1.0f / (float)PBIN);
    const float bin_w = rw * (1.0f / (float)PBIN);
    const float ct = cosf(theta);
    const float st = sinf(theta);

    const float* __restrict__ fbc = feat + ((size_t)b * C + c) * (size_t)(H * W);
    const float Hf = (float)H, Wf = (float)W;
    const float y_base = -rh * 0.5f + (float)ph * bin_h;
    const float x_base = -rw * 0.5f + (float)pw * bin_w;

    float acc = 0.0f;
    #pragma unroll
    for (int sy = 0; sy < 2; ++sy) {
        #pragma unroll
        for (int sx = 0; sx < 2; ++sx) {
            const float Y = y_base + ((float)sy + 0.5f) * bin_h * 0.5f;
            const float X = x_base + ((float)sx + 0.5f) * bin_w * 0.5f;
            float x = X * ct - Y * st + cx;
            float y = X * st + Y * ct + cy;
            const bool valid = !((y < -1.0f) || (y > Hf) || (x < -1.0f) || (x > Wf));
            float yc = fmaxf(y, 0.0f);
            float xc = fmaxf(x, 0.0f);
            int y0 = (int)yc;
            int x0 = (int)xc;
            int y1, x1;
            if (y0 >= H - 1) { y0 = H - 1; y1 = H - 1; yc = (float)y0; }
            else             { y1 = y0 + 1; }
            if (x0 >= W - 1) { x0 = W - 1; x1 = W - 1; xc = (float)x0; }
            else             { x1 = x0 + 1; }
            const float ly = yc - (float)y0, hy = 1.0f - ly;
            const float lx = xc - (float)x0, hx = 1.0f - lx;
            const float vf = valid ? 1.0f : 0.0f;
            const float w1 = hy * hx * vf, w2 = hy * lx * vf;
            const float w3 = ly * hx * vf, w4 = ly * lx * vf;
            acc += w1 * fbc[y0 * W + x0] + w2 * fbc[y0 * W + x1]
                 + w3 * fbc[y1 * W + x0] + w4 * fbc[y1 * W + x1];
        }
    }
    const float v = acc * 0.25f;
    const int lane  = threadIdx.x & 63;
    const int base  = lane & ~(NORI - 1);
    const int osrc  = (o - ind + NORI) & (NORI - 1);
    const float v0 = __shfl(v, base | osrc, 64);
    const float v1 = __shfl(v, base | ((osrc + 1) & (NORI - 1)), 64);
    out[((size_t)r * C + c) * (PBIN * PBIN) + ph * PBIN + pw] = r_var * v0 + l_var * v1;
}

extern "C" void kernel_launch(void* const* d_in, const int* in_sizes, int n_in,
                              void* d_out, int out_size, void* d_ws, size_t ws_size,
                              hipStream_t stream) {
    const float* feat = (const float*)d_in[0];   // (B, C, H, W) f32
    const float* rois = (const float*)d_in[1];   // (R, 6) f32
    float* out = (float*)d_out;

    const int R = in_sizes[1] / 6;
    const int B = in_sizes[0] / (CCH * PTOT);
    const size_t need = (size_t)B * PTOT * CCH * sizeof(float);

    if (ws_size >= need) {
        float* nhwc = (float*)d_ws;
        nchw_to_nhwc_kernel<<<dim3(B * 1024), dim3(256), 0, stream>>>(feat, nhwc);
        riroi_gather_nhwc_kernel<<<dim3(R * 4), dim3(256), 0, stream>>>(nhwc, rois, out);
    } else {
        riroi_align_rotated_kernel<<<dim3(R * PBIN * PBIN), dim3(256), 0, stream>>>(
            feat, rois, out, CCH, HH, WW);
    }
}

// Round 12
// 232.292 us; speedup vs baseline: 3.1651x; 1.1477x over previous
//
#include <hip/hip_runtime.h>
#include <hip/hip_fp16.h>

// RiRoIAlignRotated: features (B=2, C=256, H=256, W=256) f32, rois (R=512, 6)
// out (R, C, 7, 7) f32.  C = Cg(32)*O(8), o fastest. P=7, S=2, SCALE=0.25, CCW.
//
// Round-7 finding: K1 invariant at ~83us across 3 structures (conflicts 3M->0,
// occupancy 60->15%) => HBM-traffic-limited at ~2.4 TB/s for 201 MB mixed R/W.
// Harness fills/restores account for ~133us of dur_us (fixed).
// This round: fp16 NHWC workspace — halves K1 writes and K2 feature reads.
// Math stays fp32; only workspace storage is fp16.

#define NORI 8
#define PBIN 7
#define NPIX 49
#define CCH 256
#define HH 256
#define WW 256
#define PTOT (HH * WW)

struct alignas(8) Half4 { __half2 lo, hi; };

// ---------------- K1: NCHW f32 -> NHWC f16 transpose ----------------
// 128c x 128p tile, 64 KB LDS. Phase A identical to round-7 (validated):
// float4 loads + 4x4 __shfl_xor register transpose + swizzled b128 LDS write.
// Phase B: float4 LDS read -> cvt to half4 -> 8 B stores (256 B runs per p-row).
__global__ __launch_bounds__(256) void nchw_to_nhwc_f16_kernel(
    const float* __restrict__ feat, __half* __restrict__ nhwc)
{
    __shared__ float tile[128 * 128];     // [128 p][32 cq] 16B units, cq ^= p&7

    const int t = threadIdx.x;
    const int l = t & 63;                 // lane
    const int w = t >> 6;                 // wave 0..3
    const int blk = blockIdx.x;
    const int b  = blk >> 10;             // 1024 blocks per batch
    const int rest = blk & 1023;
    const int p0 = (rest >> 1) << 7;      // 512 p-tiles * 128
    const int c0 = (rest & 1) << 7;       // 2 c-tiles * 128

    const int cb = c0 + 32 * w;           // this wave's 32 channels

    // ---- phase A: 16 independent float4 loads ----
    float4 v[16];
    #pragma unroll
    for (int k = 0; k < 8; ++k) {
        #pragma unroll
        for (int h = 0; h < 2; ++h) {
            const int c  = cb + 4 * k + (l & 3);
            const int p  = p0 + 64 * h + 4 * (l >> 2);
            v[k * 2 + h] = *reinterpret_cast<const float4*>(
                feat + ((size_t)b * CCH + c) * PTOT + p);
        }
    }

    // ---- 4x4 register transpose within lane quads + b128 LDS write ----
    #pragma unroll
    for (int k = 0; k < 8; ++k) {
        #pragma unroll
        for (int h = 0; h < 2; ++h) {
            float4 a = v[k * 2 + h];
            {
                const float e0 = (l & 1) ? a.x : a.y;
                const float e1 = (l & 1) ? a.z : a.w;
                const float r0 = __shfl_xor(e0, 1, 64);
                const float r1 = __shfl_xor(e1, 1, 64);
                if (l & 1) { a.x = r0; a.z = r1; } else { a.y = r0; a.w = r1; }
            }
            {
                const float f0 = (l & 2) ? a.x : a.z;
                const float f1 = (l & 2) ? a.y : a.w;
                const float s0 = __shfl_xor(f0, 2, 64);
                const float s1 = __shfl_xor(f1, 2, 64);
                if (l & 2) { a.x = s0; a.y = s1; } else { a.z = s0; a.w = s1; }
            }
            const int p_local = 64 * h + l;
            const int cq  = 8 * w + k;                 // 16B-unit column 0..31
            const int cqs = cq ^ (p_local & 7);        // bank-quad swizzle
            *reinterpret_cast<float4*>(&tile[p_local * 128 + cqs * 4]) = a;
        }
    }
    __syncthreads();

    // ---- phase B: b128 LDS read -> f16 convert -> 8 B store ----
    __half* __restrict__ dst = nhwc + ((size_t)b * PTOT + p0) * CCH + c0;
    #pragma unroll
    for (int j = 0; j < 16; ++j) {
        const int flat = t + 256 * j;     // 0..4095
        const int p    = flat >> 5;       // 0..127
        const int cq   = flat & 31;       // 0..31
        const int cqs  = cq ^ (p & 7);
        const float4 a = *reinterpret_cast<const float4*>(&tile[p * 128 + cqs * 4]);
        Half4 hq;
        hq.lo = __half2(__float2half(a.x), __float2half(a.y));
        hq.hi = __half2(__float2half(a.z), __float2half(a.w));
        *reinterpret_cast<Half4*>(dst + (size_t)p * CCH + cq * 4) = hq;
    }
}

// ---------------- K2: gather from NHWC f16 ----------------
// block = (roi r, 64-ch quarter q). 8 ch-lanes x 8 ch (one uint4 = 8 halves
// per corner), 32 pixel-lanes, 2 passes over 49 pixels. fp32 math + fp32 LDS
// stage; orientation blend + contiguous 12.5 KB output write as before.
__global__ __launch_bounds__(256) void riroi_gather_nhwc_f16_kernel(
    const __half* __restrict__ nhwc,  // (B, H, W, C) f16
    const float* __restrict__ rois,   // (R, 6)
    float* __restrict__ out)          // (R, C, 7, 7)
{
    __shared__ float stage[64 * NPIX];   // [c_local][pix]

    const int r   = blockIdx.x >> 2;
    const int q   = blockIdx.x & 3;
    const int t   = threadIdx.x;
    const int cl8 = (t & 7) * 8;         // local channel base 0..56
    const int c8  = q * 64 + cl8;        // global channel base
    const int pixlane = t >> 3;          // 0..31

    const float* roi = rois + r * 6;
    const int   b     = (int)roi[0];
    const float cx    = roi[1] * 0.25f;
    const float cy    = roi[2] * 0.25f;
    const float rw    = fmaxf(roi[3] * 0.25f, 1.0f);
    const float rh    = fmaxf(roi[4] * 0.25f, 1.0f);
    const float theta = roi[5];

    const float ind_f     = theta * (8.0f / 6.283185307179586f);
    const float ind_floor = floorf(ind_f);
    const float l_var     = ind_f - ind_floor;
    const float r_var     = 1.0f - l_var;
    const int   ind       = (((int)ind_floor % NORI) + NORI) % NORI;

    const float bin_h = rh * (1.0f / (float)PBIN);
    const float bin_w = rw * (1.0f / (float)PBIN);
    const float ct = cosf(theta);
    const float st = sinf(theta);
    const float Hf = (float)HH, Wf = (float)WW;

    const __half* __restrict__ fb = nhwc + (size_t)b * PTOT * CCH;

    for (int pix = pixlane; pix < NPIX; pix += 32) {
        const int ph = pix / PBIN;
        const int pw = pix - ph * PBIN;
        const float y_base = -rh * 0.5f + (float)ph * bin_h;
        const float x_base = -rw * 0.5f + (float)pw * bin_w;

        float acc[8];
        #pragma unroll
        for (int i = 0; i < 8; ++i) acc[i] = 0.0f;

        #pragma unroll
        for (int sy = 0; sy < 2; ++sy) {
            #pragma unroll
            for (int sx = 0; sx < 2; ++sx) {
                const float Y = y_base + ((float)sy + 0.5f) * bin_h * 0.5f;
                const float X = x_base + ((float)sx + 0.5f) * bin_w * 0.5f;
                const float x = X * ct - Y * st + cx;
                const float y = X * st + Y * ct + cy;

                const bool valid = !((y < -1.0f) || (y > Hf) || (x < -1.0f) || (x > Wf));
                float yc = fmaxf(y, 0.0f);
                float xc = fmaxf(x, 0.0f);
                int y0 = (int)yc;
                int x0 = (int)xc;
                int y1, x1;
                if (y0 >= HH - 1) { y0 = HH - 1; y1 = HH - 1; yc = (float)y0; }
                else              { y1 = y0 + 1; }
                if (x0 >= WW - 1) { x0 = WW - 1; x1 = WW - 1; xc = (float)x0; }
                else              { x1 = x0 + 1; }

                const float ly = yc - (float)y0, hy = 1.0f - ly;
                const float lx = xc - (float)x0, hx = 1.0f - lx;
                const float vf = valid ? 1.0f : 0.0f;
                const float w1 = hy * hx * vf;
                const float w2 = hy * lx * vf;
                const float w3 = ly * hx * vf;
                const float w4 = ly * lx * vf;

                const uint4 r00 = *reinterpret_cast<const uint4*>(
                    fb + ((size_t)(y0 * WW + x0)) * CCH + c8);
                const uint4 r01 = *reinterpret_cast<const uint4*>(
                    fb + ((size_t)(y0 * WW + x1)) * CCH + c8);
                const uint4 r10 = *reinterpret_cast<const uint4*>(
                    fb + ((size_t)(y1 * WW + x0)) * CCH + c8);
                const uint4 r11 = *reinterpret_cast<const uint4*>(
                    fb + ((size_t)(y1 * WW + x1)) * CCH + c8);

                const __half2* h00 = reinterpret_cast<const __half2*>(&r00);
                const __half2* h01 = reinterpret_cast<const __half2*>(&r01);
                const __half2* h10 = reinterpret_cast<const __half2*>(&r10);
                const __half2* h11 = reinterpret_cast<const __half2*>(&r11);

                #pragma unroll
                for (int i = 0; i < 4; ++i) {
                    const float2 f00 = __half22float2(h00[i]);
                    const float2 f01 = __half22float2(h01[i]);
                    const float2 f10 = __half22float2(h10[i]);
                    const float2 f11 = __half22float2(h11[i]);
                    acc[2*i+0] += w1 * f00.x + w2 * f01.x + w3 * f10.x + w4 * f11.x;
                    acc[2*i+1] += w1 * f00.y + w2 * f01.y + w3 * f10.y + w4 * f11.y;
                }
            }
        }
        #pragma unroll
        for (int i = 0; i < 8; ++i)
            stage[(cl8 + i) * NPIX + pix] = acc[i] * 0.25f;
    }
    __syncthreads();

    // blend orientations + contiguous write of 64*49 floats
    float* __restrict__ dst = out + (size_t)r * (CCH * NPIX) + q * (64 * NPIX);
    #pragma unroll
    for (int k = 0; k < 13; ++k) {
        const int i = t + 256 * k;
        if (i < 64 * NPIX) {
            const int c   = i / NPIX;            // local out channel 0..63
            const int pix = i - c * NPIX;
            const int o   = c & (NORI - 1);
            const int s0  = (c & ~(NORI - 1)) | ((o - ind + 8) & (NORI - 1));
            const int s1  = (c & ~(NORI - 1)) | ((o - ind + 9) & (NORI - 1));
            dst[i] = r_var * stage[s0 * NPIX + pix] + l_var * stage[s1 * NPIX + pix];
        }
    }
}

// ---------------- fallback (validated round-3 kernel) ----------------
__global__ __launch_bounds__(256) void riroi_align_rotated_kernel(
    const float* __restrict__ feat, const float* __restrict__ rois,
    float* __restrict__ out, int C, int H, int W)
{
    const int blk = blockIdx.x;
    const int r   = blk / (PBIN * PBIN);
    const int pix = blk % (PBIN * PBIN);
    const int ph  = pix / PBIN;
    const int pw  = pix % PBIN;
    const int c   = threadIdx.x;
    const int o   = c & (NORI - 1);

    const float* roi = rois + r * 6;
    const int   b     = (int)roi[0];
    const float cx    = roi[1] * 0.25f;
    const float cy    = roi[2] * 0.25f;
    const float rw    = fmaxf(roi[3] * 0.25f, 1.0f);
    const float rh    = fmaxf(roi[4] * 0.25f, 1.0f);
    const float theta = roi[5];

    const float ind_f     = theta * (8.0f / 6.283185307179586f);
    const float ind_floor = floorf(ind_f);
    const float l_var     = ind_f - ind_floor;
    const float r_var     = 1.0f - l_var;
    const int ind = (((int)ind_floor % NORI) + NORI) % NORI;

    const float bin_h = rh * (1.0f / (float)PBIN);
    const float bin_w = rw * (1.0f / (float)PBIN);
    const float ct = cosf(theta);
    const float st = sinf(theta);

    const float* __restrict__ fbc = feat + ((size_t)b * C + c) * (size_t)(H * W);
    const float Hf = (float)H, Wf = (float)W;
    const float y_base = -rh * 0.5f + (float)ph * bin_h;
    const float x_base = -rw * 0.5f + (float)pw * bin_w;

    float acc = 0.0f;
    #pragma unroll
    for (int sy = 0; sy < 2; ++sy) {
        #pragma unroll
        for (int sx = 0; sx < 2; ++sx) {
            const float Y = y_base + ((float)sy + 0.5f) * bin_h * 0.5f;
            const float X = x_base + ((float)sx + 0.5f) * bin_w * 0.5f;
            float x = X * ct - Y * st + cx;
            float y = X * st + Y * ct + cy;
            const bool valid = !((y < -1.0f) || (y > Hf) || (x < -1.0f) || (x > Wf));
            float yc = fmaxf(y, 0.0f);
            float xc = fmaxf(x, 0.0f);
            int y0 = (int)yc;
            int x0 = (int)xc;
            int y1, x1;
            if (y0 >= H - 1) { y0 = H - 1; y1 = H - 1; yc = (float)y0; }
            else             { y1 = y0 + 1; }
            if (x0 >= W - 1) { x0 = W - 1; x1 = W - 1; xc = (float)x0; }
            else             { x1 = x0 + 1; }
            const float ly = yc - (float)y0, hy = 1.0f - ly;
            const float lx = xc - (float)x0, hx = 1.0f - lx;
            const float vf = valid ? 1.0f : 0.0f;
            const float w1 = hy * hx * vf, w2 = hy * lx * vf;
            const float w3 = ly * hx * vf, w4 = ly * lx * vf;
            acc += w1 * fbc[y0 * W + x0] + w2 * fbc[y0 * W + x1]
                 + w3 * fbc[y1 * W + x0] + w4 * fbc[y1 * W + x1];
        }
    }
    const float v = acc * 0.25f;
    const int lane  = threadIdx.x & 63;
    const int base  = lane & ~(NORI - 1);
    const int osrc  = (o - ind + NORI) & (NORI - 1);
    const float v0 = __shfl(v, base | osrc, 64);
    const float v1 = __shfl(v, base | ((osrc + 1) & (NORI - 1)), 64);
    out[((size_t)r * C + c) * (PBIN * PBIN) + ph * PBIN + pw] = r_var * v0 + l_var * v1;
}

extern "C" void kernel_launch(void* const* d_in, const int* in_sizes, int n_in,
                              void* d_out, int out_size, void* d_ws, size_t ws_size,
                              hipStream_t stream) {
    const float* feat = (const float*)d_in[0];   // (B, C, H, W) f32
    const float* rois = (const float*)d_in[1];   // (R, 6) f32
    float* out = (float*)d_out;

    const int R = in_sizes[1] / 6;
    const int B = in_sizes[0] / (CCH * PTOT);
    const size_t need = (size_t)B * PTOT * CCH * sizeof(__half);

    if (ws_size >= need) {
        __half* nhwc = (__half*)d_ws;
        nchw_to_nhwc_f16_kernel<<<dim3(B * 1024), dim3(256), 0, stream>>>(feat, nhwc);
        riroi_gather_nhwc_f16_kernel<<<dim3(R * 4), dim3(256), 0, stream>>>(nhwc, rois, out);
    } else {
        riroi_align_rotated_kernel<<<dim3(R * PBIN * PBIN), dim3(256), 0, stream>>>(
            feat, rois, out, CCH, HH, WW);
    }
}